// Round 1
// baseline (1137.696 us; speedup 1.0000x reference)
//
#include <hip/hip_runtime.h>

// GATGuard: 2-layer GAT with cosine-similarity edge gating (att_coef).
// N=50000 nodes, E=800000 raw edges, H=4 heads, F=64 feat/head, HF=256.
// Outputs: h1 [N,256], att_w [E], self_w [N]  (concatenated in d_out).

#define NH 4
#define NF 64
#define HF 256

__device__ __forceinline__ float wred_sum(float v) {
#pragma unroll
  for (int o = 32; o > 0; o >>= 1) v += __shfl_xor(v, o, 64);
  return v;
}
__device__ __forceinline__ float wred_max(float v) {
#pragma unroll
  for (int o = 32; o > 0; o >>= 1) v = fmaxf(v, __shfl_xor(v, o, 64));
  return v;
}
__device__ __forceinline__ float lrelu(float x, float s) {
  return x > 0.f ? x : s * x;
}

// ---------------- row inverse L2 norms (wave per row) ----------------
__global__ __launch_bounds__(256) void rownorm_kernel(
    const float* __restrict__ X, float* __restrict__ inv, int n, int D) {
  int row = blockIdx.x * 4 + (threadIdx.x >> 6);
  int lane = threadIdx.x & 63;
  if (row >= n) return;
  const float* p = X + (size_t)row * D;
  float acc = 0.f;
  for (int i = lane; i < D; i += 64) { float v = p[i]; acc += v * v; }
  acc = wred_sum(acc);
  if (lane == 0) inv[row] = 1.f / fmaxf(sqrtf(acc), 1e-12f);
}

// ---------------- layer-0 cosine threshold mask (wave per edge, D=128) ----
__global__ __launch_bounds__(256) void edge_mask_kernel(
    const float* __restrict__ X, const float* __restrict__ inv,
    const int* __restrict__ src, const int* __restrict__ dst,
    unsigned char* __restrict__ mask, int E_) {
  int e = blockIdx.x * 4 + (threadIdx.x >> 6);
  int lane = threadIdx.x & 63;
  if (e >= E_) return;
  int s = src[e], d = dst[e];
  const float* ps = X + (size_t)s * 128;
  const float* pd = X + (size_t)d * 128;
  float acc = ps[lane] * pd[lane] + ps[lane + 64] * pd[lane + 64];
  acc = wred_sum(acc);
  if (lane == 0) {
    float sim = acc * inv[s] * inv[d];
    mask[e] = (sim >= 0.1f) ? 1 : 0;
  }
}

// ---------------- att_coef #2: sim + rowsum + degree (wave per edge, D=256)
__global__ __launch_bounds__(256) void edge_sim2_kernel(
    const float* __restrict__ Hf, const float* __restrict__ inv,
    const int* __restrict__ src, const int* __restrict__ dst,
    const unsigned char* __restrict__ mask,
    float* __restrict__ sim2, float* __restrict__ rowsum,
    float* __restrict__ degf, int E_) {
  int e = blockIdx.x * 4 + (threadIdx.x >> 6);
  int lane = threadIdx.x & 63;
  if (e >= E_) return;
  int s = src[e], d = dst[e];
  const float* ps = Hf + (size_t)s * 256;
  const float* pd = Hf + (size_t)d * 256;
  float acc = ps[lane] * pd[lane] + ps[lane + 64] * pd[lane + 64] +
              ps[lane + 128] * pd[lane + 128] + ps[lane + 192] * pd[lane + 192];
  acc = wred_sum(acc);
  if (lane == 0) {
    float sim = acc * inv[s] * inv[d];
    float sv = (mask[e] && sim >= 0.1f) ? sim : 0.f;
    sim2[e] = sv;
    if (sv > 0.f) {
      atomicAdd(&rowsum[s], sv);
      atomicAdd(&degf[s], 1.0f);
    }
  }
}

// ---------------- att_w output (thread per edge) ----------------
__global__ __launch_bounds__(256) void att_w_kernel(
    const float* __restrict__ sim2, const float* __restrict__ rowsum,
    const int* __restrict__ src, float* __restrict__ out_att, int E_) {
  int e = blockIdx.x * blockDim.x + threadIdx.x;
  if (e >= E_) return;
  float sv = sim2[e];
  out_att[e] = (sv > 0.f) ? expf(sv / rowsum[src[e]]) : 0.f;
}

// ---------------- self_w output (thread per node) ----------------
__global__ __launch_bounds__(256) void self_w_kernel(
    const float* __restrict__ degf, float* __restrict__ out_self, int n) {
  int i = blockIdx.x * blockDim.x + threadIdx.x;
  if (i >= n) return;
  out_self[i] = expf(1.f / (degf[i] + 1.f));
}

// ---------------- tiled FP32 GEMM: C[n,M] = A[n,K] @ B[K,M] ----------------
// 64x64 tile, 256 threads, 4x4 microtile, K-tile 32.
__global__ __launch_bounds__(256) void gemm_kernel(
    const float* __restrict__ A, const float* __restrict__ B,
    float* __restrict__ C, int n, int K, int M) {
  __shared__ float As[32][68];  // padded (68*4B, 16B-aligned rows)
  __shared__ float Bs[32][64];
  int tid = threadIdx.x;
  int tx = tid & 15, ty = tid >> 4;
  int row0 = blockIdx.x * 64;
  int col0 = blockIdx.y * 64;
  float acc[4][4] = {};
  for (int k0 = 0; k0 < K; k0 += 32) {
#pragma unroll
    for (int i = 0; i < 2; ++i) {
      int p = tid + i * 256;     // 0..511 float4 slots of A tile (64 rows x 8 f4)
      int r = p >> 3, c4 = p & 7;
      int gr = row0 + r;
      float4 v = make_float4(0.f, 0.f, 0.f, 0.f);
      if (gr < n) v = *(const float4*)(A + (size_t)gr * K + k0 + c4 * 4);
      As[c4 * 4 + 0][r] = v.x;
      As[c4 * 4 + 1][r] = v.y;
      As[c4 * 4 + 2][r] = v.z;
      As[c4 * 4 + 3][r] = v.w;
    }
#pragma unroll
    for (int i = 0; i < 2; ++i) {
      int p = tid + i * 256;     // 32 rows x 16 f4
      int r = p >> 4, c4 = p & 15;
      float4 v = *(const float4*)(B + (size_t)(k0 + r) * M + col0 + c4 * 4);
      *(float4*)&Bs[r][c4 * 4] = v;
    }
    __syncthreads();
#pragma unroll
    for (int k = 0; k < 32; ++k) {
      float4 ra = *(const float4*)&As[k][ty * 4];
      float4 rb = *(const float4*)&Bs[k][tx * 4];
      float a_[4] = {ra.x, ra.y, ra.z, ra.w};
      float b_[4] = {rb.x, rb.y, rb.z, rb.w};
#pragma unroll
      for (int i = 0; i < 4; ++i)
#pragma unroll
        for (int j = 0; j < 4; ++j) acc[i][j] += a_[i] * b_[j];
    }
    __syncthreads();
  }
#pragma unroll
  for (int i = 0; i < 4; ++i) {
    int gr = row0 + ty * 4 + i;
    if (gr < n) {
      float4 v = make_float4(acc[i][0], acc[i][1], acc[i][2], acc[i][3]);
      *(float4*)(C + (size_t)gr * M + col0 + tx * 4) = v;
    }
  }
}

// ---------------- el/er per (node, head) ----------------
__global__ __launch_bounds__(256) void elr_kernel(
    const float* __restrict__ feat, const float* __restrict__ a,
    float* __restrict__ el, float* __restrict__ er, int n) {
  int node = blockIdx.x;
  int lane = threadIdx.x & 63;
  int wv = threadIdx.x >> 6;
  if (node >= n) return;
  float f = feat[(size_t)node * HF + wv * NF + lane];
  float p0 = f * a[wv * NF + lane];          // a[0,h,f]
  float p1 = f * a[HF + wv * NF + lane];     // a[1,h,f]
  p0 = wred_sum(p0);
  p1 = wred_sum(p1);
  if (lane == 0) {
    el[node * NH + wv] = p0;
    er[node * NH + wv] = p1;
  }
}

// ---------------- CSR build ----------------
__global__ __launch_bounds__(256) void hist_kernel(
    const int* __restrict__ dst, int* __restrict__ deg, int E_) {
  int e = blockIdx.x * blockDim.x + threadIdx.x;
  if (e >= E_) return;
  atomicAdd(&deg[dst[e]], 1);
}

__global__ __launch_bounds__(1024) void scan_kernel(
    const int* __restrict__ deg, int* __restrict__ rs, int n) {
  __shared__ int temp[1024];
  __shared__ int carry_s;
  int tid = threadIdx.x;
  if (tid == 0) carry_s = 0;
  __syncthreads();
  for (int base = 0; base < n; base += 1024) {
    int idx = base + tid;
    int v = (idx < n) ? deg[idx] : 0;
    temp[tid] = v;
    __syncthreads();
    for (int off = 1; off < 1024; off <<= 1) {
      int t = (tid >= off) ? temp[tid - off] : 0;
      __syncthreads();
      temp[tid] += t;
      __syncthreads();
    }
    int incl = temp[tid];
    int carry = carry_s;
    if (idx < n) rs[idx] = carry + incl - v;  // exclusive
    __syncthreads();
    if (tid == 1023) carry_s = carry + temp[1023];
    __syncthreads();
  }
  if (tid == 0) rs[n] = carry_s;
}

__global__ __launch_bounds__(256) void scatter_kernel(
    const int* __restrict__ src, const int* __restrict__ dst,
    const int* __restrict__ rs, int* __restrict__ cursor,
    int* __restrict__ csr_src, int E_) {
  int e = blockIdx.x * blockDim.x + threadIdx.x;
  if (e >= E_) return;
  int d = dst[e];
  int pos = rs[d] + atomicAdd(&cursor[d], 1);
  csr_src[pos] = src[e];
}

// ---------------- GAT aggregation (block per node, wave per head) ---------
__global__ __launch_bounds__(256) void gat_agg_kernel(
    const float* __restrict__ feat, const float* __restrict__ el,
    const float* __restrict__ er, const int* __restrict__ row_start,
    const int* __restrict__ csr_src, const float* __restrict__ bias,
    float* __restrict__ out, int n, int act) {
  int node = blockIdx.x;
  int tid = threadIdx.x;
  int lane = tid & 63;
  int wv = tid >> 6;  // head
  __shared__ float wbuf[NH][64];
  __shared__ int sbuf[NH][64];
  float er_n = er[node * NH + wv];
  float el_n = el[node * NH + wv];
  float es = lrelu(el_n + er_n, 0.2f);  // self-loop score
  int start = row_start[node];
  int deg = row_start[node + 1] - start;
  // phase 1: max over incoming edges + self
  float m = es;
  for (int i = lane; i < deg; i += 64) {
    int s = csr_src[start + i];
    m = fmaxf(m, lrelu(el[s * NH + wv] + er_n, 0.2f));
  }
  m = wred_max(m);
  // phase 2: chunked exp-weights + feature accumulation
  float ws = __expf(es - m);
  float acc = ws * feat[(size_t)node * HF + wv * NF + lane];
  float zl = 0.f;
  int nch = (deg + 63) >> 6;
  for (int c = 0; c < nch; ++c) {
    int i = c * 64 + lane;
    float w = 0.f;
    int s = 0;
    if (i < deg) {
      s = csr_src[start + i];
      w = __expf(lrelu(el[s * NH + wv] + er_n, 0.2f) - m);
    }
    zl += w;
    wbuf[wv][lane] = w;
    sbuf[wv][lane] = s;
    __syncthreads();
    int cnt = min(64, deg - c * 64);
    for (int j = 0; j < cnt; ++j) {
      float wj = wbuf[wv][j];
      int sj = sbuf[wv][j];
      acc += wj * feat[(size_t)sj * HF + wv * NF + lane];
    }
    __syncthreads();
  }
  float z = wred_sum(zl) + ws;
  float o_ = acc / z + bias[wv * NF + lane];
  if (act) o_ = lrelu(o_, 0.01f);
  out[(size_t)node * HF + wv * NF + lane] = o_;
}

extern "C" void kernel_launch(void* const* d_in, const int* in_sizes, int n_in,
                              void* d_out, int out_size, void* d_ws, size_t ws_size,
                              hipStream_t stream) {
  const float* x = (const float*)d_in[0];
  const int* esrc = (const int*)d_in[1];
  const int* edst = (const int*)d_in[2];
  const float* W0 = (const float*)d_in[3];
  const float* a0 = (const float*)d_in[4];
  const float* b0 = (const float*)d_in[5];
  const float* W1 = (const float*)d_in[6];
  const float* a1 = (const float*)d_in[7];
  const float* b1 = (const float*)d_in[8];

  const int N = in_sizes[0] / 128;  // 50000
  const int E = in_sizes[1];        // 800000

  // ---- workspace layout (256B aligned chunks) ----
  char* wp = (char*)d_ws;
  auto alloc = [&](size_t bytes) {
    char* p = wp;
    wp += (bytes + 255) & ~(size_t)255;
    return p;
  };
  float* h0 = (float*)alloc((size_t)N * HF * 4);
  float* featb = (float*)alloc((size_t)N * HF * 4);
  float* xinv = (float*)alloc((size_t)N * 4);
  float* h0inv = (float*)alloc((size_t)N * 4);
  float* el = (float*)alloc((size_t)N * NH * 4);
  float* er = (float*)alloc((size_t)N * NH * 4);
  unsigned char* mask1 = (unsigned char*)alloc((size_t)E);
  float* sim2 = (float*)alloc((size_t)E * 4);
  float* rowsum = (float*)alloc((size_t)N * 4);
  float* degf = (float*)alloc((size_t)N * 4);
  int* deg_i = (int*)alloc((size_t)N * 4);
  int* row_start = (int*)alloc((size_t)(N + 1) * 4);
  int* cursor = (int*)alloc((size_t)N * 4);
  int* csr_src = (int*)alloc((size_t)E * 4);

  float* out_h = (float*)d_out;            // [N,256]
  float* out_att = out_h + (size_t)N * HF; // [E]
  float* out_self = out_att + E;           // [N]

  const int EB4 = (E + 3) / 4;        // wave-per-edge grids
  const int NB4 = (N + 3) / 4;
  const int EBT = (E + 255) / 256;    // thread-per-edge grids
  const int NBT = (N + 255) / 256;

  // ---- zero accumulators (ws is poisoned before every call) ----
  hipMemsetAsync(deg_i, 0, (size_t)N * 4, stream);
  hipMemsetAsync(cursor, 0, (size_t)N * 4, stream);
  hipMemsetAsync(rowsum, 0, (size_t)N * 4, stream);
  hipMemsetAsync(degf, 0, (size_t)N * 4, stream);

  // ---- CSR by dst (topology fixed for both layers) ----
  hist_kernel<<<EBT, 256, 0, stream>>>(edst, deg_i, E);
  scan_kernel<<<1, 1024, 0, stream>>>(deg_i, row_start, N);
  scatter_kernel<<<EBT, 256, 0, stream>>>(esrc, edst, row_start, cursor, csr_src, E);

  // ---- att_coef #1 on x: only the mask survives ----
  rownorm_kernel<<<NB4, 256, 0, stream>>>(x, xinv, N, 128);
  edge_mask_kernel<<<EB4, 256, 0, stream>>>(x, xinv, esrc, edst, mask1, E);

  // ---- layer 0: feat = x@W0; el/er; aggregate -> h0 (leaky_relu 0.01) ----
  {
    dim3 g((N + 63) / 64, HF / 64);
    gemm_kernel<<<g, 256, 0, stream>>>(x, W0, featb, N, 128, HF);
  }
  elr_kernel<<<N, 256, 0, stream>>>(featb, a0, el, er, N);
  gat_agg_kernel<<<N, 256, 0, stream>>>(featb, el, er, row_start, csr_src, b0, h0, N, 1);

  // ---- att_coef #2 on h0: produces att_w, self_w outputs ----
  rownorm_kernel<<<NB4, 256, 0, stream>>>(h0, h0inv, N, 256);
  edge_sim2_kernel<<<EB4, 256, 0, stream>>>(h0, h0inv, esrc, edst, mask1, sim2,
                                            rowsum, degf, E);
  att_w_kernel<<<EBT, 256, 0, stream>>>(sim2, rowsum, esrc, out_att, E);
  self_w_kernel<<<NBT, 256, 0, stream>>>(degf, out_self, N);

  // ---- layer 1: feat = h0@W1; el/er; aggregate -> out_h (no act) ----
  {
    dim3 g((N + 63) / 64, HF / 64);
    gemm_kernel<<<g, 256, 0, stream>>>(h0, W1, featb, N, 256, HF);
  }
  elr_kernel<<<N, 256, 0, stream>>>(featb, a1, el, er, N);
  gat_agg_kernel<<<N, 256, 0, stream>>>(featb, el, er, row_start, csr_src, b1,
                                        out_h, N, 0);
}

// Round 2
// 934.403 us; speedup vs baseline: 1.2176x; 1.2176x over previous
//
#include <hip/hip_runtime.h>

// GATGuard: 2-layer GAT with cosine-similarity edge gating (att_coef).
// N=50000 nodes, E=800000 raw edges, H=4 heads, F=64 feat/head, HF=256.
// Outputs: h1 [N,256], att_w [E], self_w [N]  (concatenated in d_out).

#define NH 4
#define NF 64
#define HF 256

__device__ __forceinline__ float wred_sum(float v) {
#pragma unroll
  for (int o = 32; o > 0; o >>= 1) v += __shfl_xor(v, o, 64);
  return v;
}
__device__ __forceinline__ float lrelu(float x, float s) {
  return x > 0.f ? x : s * x;
}

// ---------------- row inverse L2 norms (wave per row) ----------------
__global__ __launch_bounds__(256) void rownorm_kernel(
    const float* __restrict__ X, float* __restrict__ inv, int n, int D) {
  int row = blockIdx.x * 4 + (threadIdx.x >> 6);
  int lane = threadIdx.x & 63;
  if (row >= n) return;
  const float* p = X + (size_t)row * D;
  float acc = 0.f;
  for (int i = lane; i < D; i += 64) { float v = p[i]; acc += v * v; }
  acc = wred_sum(acc);
  if (lane == 0) inv[row] = 1.f / fmaxf(sqrtf(acc), 1e-12f);
}

// ---------------- layer-0 cosine threshold mask (wave per edge, D=128) ----
__global__ __launch_bounds__(256) void edge_mask_kernel(
    const float* __restrict__ X, const float* __restrict__ inv,
    const int* __restrict__ src, const int* __restrict__ dst,
    unsigned char* __restrict__ mask, int E_) {
  int e = blockIdx.x * 4 + (threadIdx.x >> 6);
  int lane = threadIdx.x & 63;
  if (e >= E_) return;
  int s = src[e], d = dst[e];
  const float2* ps = (const float2*)(X + (size_t)s * 128);
  const float2* pd = (const float2*)(X + (size_t)d * 128);
  float2 a = ps[lane], b = pd[lane];
  float acc = a.x * b.x + a.y * b.y;
  acc = wred_sum(acc);
  if (lane == 0) {
    float sim = acc * inv[s] * inv[d];
    mask[e] = (sim >= 0.1f) ? 1 : 0;
  }
}

// ---- att_coef #2: sim + rowsum + degree (wave per edge, D=256) ----
// Early-exit on the layer-0 mask: ~87% of edges skip the 2 KB row gather.
__global__ __launch_bounds__(256) void edge_sim2_kernel(
    const float* __restrict__ Hf, const float* __restrict__ inv,
    const int* __restrict__ src, const int* __restrict__ dst,
    const unsigned char* __restrict__ mask,
    float* __restrict__ sim2, float* __restrict__ rowsum,
    float* __restrict__ degf, int E_) {
  int e = blockIdx.x * 4 + (threadIdx.x >> 6);
  int lane = threadIdx.x & 63;
  if (e >= E_) return;
  if (!mask[e]) {
    if (lane == 0) sim2[e] = 0.f;
    return;
  }
  int s = src[e], d = dst[e];
  const float4* ps = (const float4*)(Hf + (size_t)s * 256);
  const float4* pd = (const float4*)(Hf + (size_t)d * 256);
  float4 a = ps[lane], b = pd[lane];
  float acc = a.x * b.x + a.y * b.y + a.z * b.z + a.w * b.w;
  acc = wred_sum(acc);
  if (lane == 0) {
    float sim = acc * inv[s] * inv[d];
    float sv = (sim >= 0.1f) ? sim : 0.f;
    sim2[e] = sv;
    if (sv > 0.f) {
      atomicAdd(&rowsum[s], sv);
      atomicAdd(&degf[s], 1.0f);
    }
  }
}

// ---------------- att_w output (thread per edge) ----------------
__global__ __launch_bounds__(256) void att_w_kernel(
    const float* __restrict__ sim2, const float* __restrict__ rowsum,
    const int* __restrict__ src, float* __restrict__ out_att, int E_) {
  int e = blockIdx.x * blockDim.x + threadIdx.x;
  if (e >= E_) return;
  float sv = sim2[e];
  out_att[e] = (sv > 0.f) ? expf(sv / rowsum[src[e]]) : 0.f;
}

// ---------------- self_w output (thread per node) ----------------
__global__ __launch_bounds__(256) void self_w_kernel(
    const float* __restrict__ degf, float* __restrict__ out_self, int n) {
  int i = blockIdx.x * blockDim.x + threadIdx.x;
  if (i >= n) return;
  out_self[i] = expf(1.f / (degf[i] + 1.f));
}

// ---------------- tiled FP32 GEMM: C[n,M] = A[n,K] @ B[K,M] ----------------
// 128x128 tile, 256 threads, 8x8 microtile, K-tile 16.
// LDS intensity: 2 flop/byte (ceiling ~157 TF). A-reads broadcast, B-reads
// 2-way (free). Micro-tile cols split tx*4 / 64+tx*4 to avoid 4-way conflicts.
__global__ __launch_bounds__(256) void gemm_kernel(
    const float* __restrict__ A, const float* __restrict__ B,
    float* __restrict__ C, int n, int K, int M) {
  __shared__ float As[16][128];
  __shared__ float Bs[16][128];
  int tid = threadIdx.x;
  int tx = tid & 15, ty = tid >> 4;
  int row0 = blockIdx.x * 128;
  int col0 = blockIdx.y * 128;
  float acc[8][8] = {};
  for (int k0 = 0; k0 < K; k0 += 16) {
    // A tile: 128 rows x 16 k = 512 float4, transpose into As[k][row]
#pragma unroll
    for (int i = 0; i < 2; ++i) {
      int p = tid + i * 256;
      int r = p >> 2, c4 = p & 3;
      int gr = row0 + r;
      float4 v = make_float4(0.f, 0.f, 0.f, 0.f);
      if (gr < n) v = *(const float4*)(A + (size_t)gr * K + k0 + c4 * 4);
      As[c4 * 4 + 0][r] = v.x;
      As[c4 * 4 + 1][r] = v.y;
      As[c4 * 4 + 2][r] = v.z;
      As[c4 * 4 + 3][r] = v.w;
    }
    // B tile: 16 rows x 128 cols = 512 float4, direct copy
#pragma unroll
    for (int i = 0; i < 2; ++i) {
      int p = tid + i * 256;
      int r = p >> 5, c4 = p & 31;
      *(float4*)&Bs[r][c4 * 4] =
          *(const float4*)(B + (size_t)(k0 + r) * M + col0 + c4 * 4);
    }
    __syncthreads();
#pragma unroll
    for (int k = 0; k < 16; ++k) {
      float4 a0v = *(const float4*)&As[k][ty * 4];
      float4 a1v = *(const float4*)&As[k][64 + ty * 4];
      float4 b0v = *(const float4*)&Bs[k][tx * 4];
      float4 b1v = *(const float4*)&Bs[k][64 + tx * 4];
      float av[8] = {a0v.x, a0v.y, a0v.z, a0v.w, a1v.x, a1v.y, a1v.z, a1v.w};
      float bv[8] = {b0v.x, b0v.y, b0v.z, b0v.w, b1v.x, b1v.y, b1v.z, b1v.w};
#pragma unroll
      for (int i = 0; i < 8; ++i)
#pragma unroll
        for (int j = 0; j < 8; ++j) acc[i][j] += av[i] * bv[j];
    }
    __syncthreads();
  }
#pragma unroll
  for (int half = 0; half < 2; ++half) {
#pragma unroll
    for (int i = 0; i < 4; ++i) {
      int gr = row0 + half * 64 + ty * 4 + i;
      if (gr < n) {
        float* cp = C + (size_t)gr * M + col0;
        int ai = half * 4 + i;
        *(float4*)(cp + tx * 4) =
            make_float4(acc[ai][0], acc[ai][1], acc[ai][2], acc[ai][3]);
        *(float4*)(cp + 64 + tx * 4) =
            make_float4(acc[ai][4], acc[ai][5], acc[ai][6], acc[ai][7]);
      }
    }
  }
}

// ---------------- el/er per (node, head) ----------------
__global__ __launch_bounds__(256) void elr_kernel(
    const float* __restrict__ feat, const float* __restrict__ a,
    float* __restrict__ el, float* __restrict__ er, int n) {
  int node = blockIdx.x;
  int lane = threadIdx.x & 63;
  int wv = threadIdx.x >> 6;
  if (node >= n) return;
  float f = feat[(size_t)node * HF + wv * NF + lane];
  float p0 = f * a[wv * NF + lane];          // a[0,h,f]
  float p1 = f * a[HF + wv * NF + lane];     // a[1,h,f]
  p0 = wred_sum(p0);
  p1 = wred_sum(p1);
  if (lane == 0) {
    el[node * NH + wv] = p0;
    er[node * NH + wv] = p1;
  }
}

// ---------------- CSR build ----------------
__global__ __launch_bounds__(256) void hist_kernel(
    const int* __restrict__ dst, int* __restrict__ deg, int E_) {
  int e = blockIdx.x * blockDim.x + threadIdx.x;
  if (e >= E_) return;
  atomicAdd(&deg[dst[e]], 1);
}

// 3-phase scan: per-block scan -> scan of block sums -> add offsets.
__global__ __launch_bounds__(1024) void scanA_kernel(
    const int* __restrict__ deg, int* __restrict__ rs, int* __restrict__ bsum,
    int n) {
  __shared__ int temp[1024];
  int tid = threadIdx.x;
  int idx = blockIdx.x * 1024 + tid;
  int v = (idx < n) ? deg[idx] : 0;
  temp[tid] = v;
  __syncthreads();
  for (int off = 1; off < 1024; off <<= 1) {
    int t = (tid >= off) ? temp[tid - off] : 0;
    __syncthreads();
    temp[tid] += t;
    __syncthreads();
  }
  if (idx < n) rs[idx] = temp[tid] - v;  // block-local exclusive
  if (tid == 1023) bsum[blockIdx.x] = temp[1023];
}

__global__ void scanB_kernel(int* __restrict__ bsum, int nb) {
  if (threadIdx.x == 0) {
    int run = 0;
    for (int i = 0; i < nb; ++i) {
      int v = bsum[i];
      bsum[i] = run;
      run += v;
    }
    bsum[nb] = run;
  }
}

__global__ __launch_bounds__(256) void scanC_kernel(
    int* __restrict__ rs, const int* __restrict__ bsum, int n, int nb) {
  int idx = blockIdx.x * blockDim.x + threadIdx.x;
  if (idx < n) rs[idx] += bsum[idx >> 10];
  else if (idx == n) rs[n] = bsum[nb];
}

__global__ __launch_bounds__(256) void scatter_kernel(
    const int* __restrict__ src, const int* __restrict__ dst,
    const int* __restrict__ rs, int* __restrict__ cursor,
    int* __restrict__ csr_src, int E_) {
  int e = blockIdx.x * blockDim.x + threadIdx.x;
  if (e >= E_) return;
  int d = dst[e];
  int pos = rs[d] + atomicAdd(&cursor[d], 1);
  csr_src[pos] = src[e];
}

// ---------------- GAT aggregation (wave per node, float4 per lane) -------
// lane l serves head h=l>>4, features h*64 + (l&15)*4 .. +3.
// Per edge: 1 KB coalesced feat row + one 16 B el line. No LDS, no barriers.
__global__ __launch_bounds__(256) void gat_agg_kernel(
    const float* __restrict__ feat, const float* __restrict__ el,
    const float* __restrict__ er, const int* __restrict__ row_start,
    const int* __restrict__ csr_src, const float* __restrict__ bias,
    float* __restrict__ out, float* __restrict__ inv_out, int n, int act) {
  int node = blockIdx.x * 4 + (threadIdx.x >> 6);
  int lane = threadIdx.x & 63;
  if (node >= n) return;
  int h = lane >> 4;
  int il = lane & 15;
  const float4* feat4 = (const float4*)feat;
  float er_n = er[node * NH + h];
  float es = lrelu(el[node * NH + h] + er_n, 0.2f);
  int start = row_start[node];
  int deg = row_start[node + 1] - start;
  // phase 1: per-head max over incoming edges + self (16 lanes stride)
  float m = es;
  for (int i = il; i < deg; i += 16) {
    int s = csr_src[start + i];
    m = fmaxf(m, lrelu(el[s * NH + h] + er_n, 0.2f));
  }
#pragma unroll
  for (int o = 1; o < 16; o <<= 1) m = fmaxf(m, __shfl_xor(m, o, 64));
  // phase 2: serial edge loop, w uniform within each 16-lane head group
  float ws = __expf(es - m);
  float4 fv = feat4[(size_t)node * 64 + lane];
  float4 facc = make_float4(ws * fv.x, ws * fv.y, ws * fv.z, ws * fv.w);
  float z = ws;
#pragma unroll 4
  for (int j = 0; j < deg; ++j) {
    int s = csr_src[start + j];
    float w = __expf(lrelu(el[s * NH + h] + er_n, 0.2f) - m);
    float4 f = feat4[(size_t)s * 64 + lane];
    facc.x += w * f.x;
    facc.y += w * f.y;
    facc.z += w * f.z;
    facc.w += w * f.w;
    z += w;
  }
  float rz = 1.f / z;
  float4 bb = ((const float4*)bias)[lane];
  float4 o_;
  o_.x = facc.x * rz + bb.x;
  o_.y = facc.y * rz + bb.y;
  o_.z = facc.z * rz + bb.z;
  o_.w = facc.w * rz + bb.w;
  if (act) {
    o_.x = lrelu(o_.x, 0.01f);
    o_.y = lrelu(o_.y, 0.01f);
    o_.z = lrelu(o_.z, 0.01f);
    o_.w = lrelu(o_.w, 0.01f);
  }
  ((float4*)out)[(size_t)node * 64 + lane] = o_;
  if (inv_out) {  // fused row-norm for the next att_coef
    float sq = o_.x * o_.x + o_.y * o_.y + o_.z * o_.z + o_.w * o_.w;
    sq = wred_sum(sq);
    if (lane == 0) inv_out[node] = 1.f / fmaxf(sqrtf(sq), 1e-12f);
  }
}

extern "C" void kernel_launch(void* const* d_in, const int* in_sizes, int n_in,
                              void* d_out, int out_size, void* d_ws, size_t ws_size,
                              hipStream_t stream) {
  const float* x = (const float*)d_in[0];
  const int* esrc = (const int*)d_in[1];
  const int* edst = (const int*)d_in[2];
  const float* W0 = (const float*)d_in[3];
  const float* a0 = (const float*)d_in[4];
  const float* b0 = (const float*)d_in[5];
  const float* W1 = (const float*)d_in[6];
  const float* a1 = (const float*)d_in[7];
  const float* b1 = (const float*)d_in[8];

  const int N = in_sizes[0] / 128;  // 50000
  const int E = in_sizes[1];        // 800000

  // ---- workspace layout (256B aligned chunks) ----
  char* wp = (char*)d_ws;
  auto alloc = [&](size_t bytes) {
    char* p = wp;
    wp += (bytes + 255) & ~(size_t)255;
    return p;
  };
  float* h0 = (float*)alloc((size_t)N * HF * 4);
  float* featb = (float*)alloc((size_t)N * HF * 4);
  float* xinv = (float*)alloc((size_t)N * 4);
  float* h0inv = (float*)alloc((size_t)N * 4);
  float* el = (float*)alloc((size_t)N * NH * 4);
  float* er = (float*)alloc((size_t)N * NH * 4);
  unsigned char* mask1 = (unsigned char*)alloc((size_t)E);
  float* sim2 = (float*)alloc((size_t)E * 4);
  float* rowsum = (float*)alloc((size_t)N * 4);
  float* degf = (float*)alloc((size_t)N * 4);
  int* deg_i = (int*)alloc((size_t)N * 4);
  int* row_start = (int*)alloc((size_t)(N + 1) * 4);
  int* cursor = (int*)alloc((size_t)N * 4);
  int* csr_src = (int*)alloc((size_t)E * 4);
  const int NSB = (N + 1023) / 1024;  // scan blocks
  int* bsum = (int*)alloc((size_t)(NSB + 1) * 4);

  float* out_h = (float*)d_out;            // [N,256]
  float* out_att = out_h + (size_t)N * HF; // [E]
  float* out_self = out_att + E;           // [N]

  const int EB4 = (E + 3) / 4;        // wave-per-edge grids
  const int NB4 = (N + 3) / 4;
  const int EBT = (E + 255) / 256;    // thread-per-edge grids
  const int NBT = (N + 255) / 256;

  // ---- zero accumulators (ws is poisoned before every call) ----
  hipMemsetAsync(deg_i, 0, (size_t)N * 4, stream);
  hipMemsetAsync(cursor, 0, (size_t)N * 4, stream);
  hipMemsetAsync(rowsum, 0, (size_t)N * 4, stream);
  hipMemsetAsync(degf, 0, (size_t)N * 4, stream);

  // ---- CSR by dst (topology fixed for both layers) ----
  hist_kernel<<<EBT, 256, 0, stream>>>(edst, deg_i, E);
  scanA_kernel<<<NSB, 1024, 0, stream>>>(deg_i, row_start, bsum, N);
  scanB_kernel<<<1, 64, 0, stream>>>(bsum, NSB);
  scanC_kernel<<<(N + 256) / 256, 256, 0, stream>>>(row_start, bsum, N, NSB);
  scatter_kernel<<<EBT, 256, 0, stream>>>(esrc, edst, row_start, cursor, csr_src, E);

  // ---- att_coef #1 on x: only the mask survives ----
  rownorm_kernel<<<NB4, 256, 0, stream>>>(x, xinv, N, 128);
  edge_mask_kernel<<<EB4, 256, 0, stream>>>(x, xinv, esrc, edst, mask1, E);

  // ---- layer 0: feat = x@W0; el/er; aggregate -> h0 (leaky_relu 0.01) ----
  {
    dim3 g((N + 127) / 128, HF / 128);
    gemm_kernel<<<g, 256, 0, stream>>>(x, W0, featb, N, 128, HF);
  }
  elr_kernel<<<N, 256, 0, stream>>>(featb, a0, el, er, N);
  gat_agg_kernel<<<NB4, 256, 0, stream>>>(featb, el, er, row_start, csr_src,
                                          b0, h0, h0inv, N, 1);

  // ---- att_coef #2 on h0: produces att_w, self_w outputs ----
  edge_sim2_kernel<<<EB4, 256, 0, stream>>>(h0, h0inv, esrc, edst, mask1, sim2,
                                            rowsum, degf, E);
  att_w_kernel<<<EBT, 256, 0, stream>>>(sim2, rowsum, esrc, out_att, E);
  self_w_kernel<<<NBT, 256, 0, stream>>>(degf, out_self, N);

  // ---- layer 1: feat = h0@W1; el/er; aggregate -> out_h (no act) ----
  {
    dim3 g((N + 127) / 128, HF / 128);
    gemm_kernel<<<g, 256, 0, stream>>>(h0, W1, featb, N, 256, HF);
  }
  elr_kernel<<<N, 256, 0, stream>>>(featb, a1, el, er, N);
  gat_agg_kernel<<<NB4, 256, 0, stream>>>(featb, el, er, row_start, csr_src,
                                          b1, out_h, nullptr, N, 0);
}